// Round 2
// baseline (125102.759 us; speedup 1.0000x reference)
//
#include <hip/hip_runtime.h>

#define NSTATE 16
#define H1 75
#define CHUNK 256

// ViterbiNet, exact numpy-float32 replication:
//  priors: h = fl(fl(rx*W1[k]) + b1[k]) (mul+add, NOT fma), relu,
//          acc = sequential fmaf over k=0..74 (BLAS microkernel order),
//          prior = fl(acc + b2[j]).
//  ACS:    v = fl(u - p), pairwise fmin; bit = parity of FIRST argmin
//          (strict-< chain == numpy first-occurrence tie rule; f32 exact
//          ties are frequent at |u|~1e5, so tie order matters).
__launch_bounds__(1024, 1)
__global__ void viterbi_fused_f32(const float* __restrict__ rx,
                                  const float* __restrict__ W1,
                                  const float* __restrict__ b1,
                                  const float* __restrict__ W2,
                                  const float* __restrict__ b2,
                                  float* __restrict__ out, int T) {
  __shared__ float q_lds[CHUNK][NSTATE];  // priors for this chunk
  const int tid = (int)threadIdx.x;
  const int lane = tid & 63;

  // 8 distinct state metrics (trellis rows 8..15 duplicate 0..7)
  float u0 = 0.f, u1 = 0.f, u2 = 0.f, u3 = 0.f,
        u4 = 0.f, u5 = 0.f, u6 = 0.f, u7 = 0.f;
  float mybit = 0.f;

  for (int base = 0; base < T; base += CHUNK) {
    const int nsteps = min(CHUNK, T - base);

    // ---- Phase P (all 1024 threads): priors in exact numpy-f32 order
    for (int id = tid; id < nsteps * NSTATE; id += 1024) {
      const int tl = id >> 4;
      const int j = id & 15;
      const float rxv = rx[base + tl];
      float acc = 0.f;
      for (int k = 0; k < H1; ++k) {
        float h = __fadd_rn(__fmul_rn(rxv, W1[k]), b1[k]);  // no contraction
        h = fmaxf(h, 0.f);
        acc = __fmaf_rn(h, W2[k * NSTATE + j], acc);        // sequential k FMA
      }
      q_lds[tl][j] = __fadd_rn(acc, b2[j]);
    }
    __syncthreads();

    // ---- Phase C (wave 0 only): sequential ACS over the chunk
    if (tid < 64) {
      for (int tl = 0; tl < nsteps; ++tl) {
        const int t = base + tl;
        // bit = parity of first argmin of pre-update metrics.
        // in_prob = [u0..u7, u0..u7]; first min occurs in first 8.
        float m = u0; int arg = 0;
        if (u1 < m) { m = u1; arg = 1; }
        if (u2 < m) { m = u2; arg = 2; }
        if (u3 < m) { m = u3; arg = 3; }
        if (u4 < m) { m = u4; arg = 4; }
        if (u5 < m) { m = u5; arg = 5; }
        if (u6 < m) { m = u6; arg = 6; }
        if (u7 < m) { m = u7; arg = 7; }
        const float bit = (float)(arg & 1);
        if ((t & 63) == lane) mybit = bit;
        if (((t & 63) == 63) || (t == T - 1)) {
          if (lane <= (t & 63)) out[(t & ~63) + lane] = mybit;
        }
        // v[j] = in_prob[j] - prior[j]; in_prob[j] = u[j&7]
        const float* q = q_lds[tl];
        const float v0  = __fsub_rn(u0, q[0]),  v1  = __fsub_rn(u1, q[1]);
        const float v2  = __fsub_rn(u2, q[2]),  v3  = __fsub_rn(u3, q[3]);
        const float v4  = __fsub_rn(u4, q[4]),  v5  = __fsub_rn(u5, q[5]);
        const float v6  = __fsub_rn(u6, q[6]),  v7  = __fsub_rn(u7, q[7]);
        const float v8  = __fsub_rn(u0, q[8]),  v9  = __fsub_rn(u1, q[9]);
        const float v10 = __fsub_rn(u2, q[10]), v11 = __fsub_rn(u3, q[11]);
        const float v12 = __fsub_rn(u4, q[12]), v13 = __fsub_rn(u5, q[13]);
        const float v14 = __fsub_rn(u6, q[14]), v15 = __fsub_rn(u7, q[15]);
        u0 = fminf(v0, v1);
        u1 = fminf(v2, v3);
        u2 = fminf(v4, v5);
        u3 = fminf(v6, v7);
        u4 = fminf(v8, v9);
        u5 = fminf(v10, v11);
        u6 = fminf(v12, v13);
        u7 = fminf(v14, v15);
      }
    }
    __syncthreads();
  }
}

extern "C" void kernel_launch(void* const* d_in, const int* in_sizes, int n_in,
                              void* d_out, int out_size, void* d_ws, size_t ws_size,
                              hipStream_t stream) {
  const float* rx = (const float*)d_in[0];
  const float* W1 = (const float*)d_in[1];
  const float* b1 = (const float*)d_in[2];
  const float* W2 = (const float*)d_in[3];
  const float* b2 = (const float*)d_in[4];
  float* out = (float*)d_out;
  const int T = in_sizes[0];
  viterbi_fused_f32<<<1, 1024, 0, stream>>>(rx, W1, b1, W2, b2, out, T);
}

// Round 4
// 102852.332 us; speedup vs baseline: 1.2163x; 1.2163x over previous
//
#include <hip/hip_runtime.h>

#define NSTATE 16
#define H1 75
#define CHUNK 256
#define NPROD 960  // threads in waves 1..15

// Round 4: round-2 kernel (PASSING, exact numpy-f32 arithmetic) with ONE
// change: priors for chunk c+1 are computed by waves 1..15 concurrently with
// wave 0's serial ACS on chunk c (double-buffered q_lds, one barrier per
// chunk). Serial body, bit extraction, and prior math are byte-identical to
// the passing version. Isolates the "producer overlap" mechanism.
__launch_bounds__(1024, 1)
__global__ void viterbi_pipe2(const float* __restrict__ rx,
                              const float* __restrict__ W1,
                              const float* __restrict__ b1,
                              const float* __restrict__ W2,
                              const float* __restrict__ b2,
                              float* __restrict__ out, int T) {
  __shared__ float q_lds[2][CHUNK][NSTATE];
  const int tid = (int)threadIdx.x;
  const int lane = tid & 63;
  const int nchunks = (T + CHUNK - 1) / CHUNK;

  // ---- prologue: priors for chunk 0 (all 1024 threads) ----
  {
    const int n0 = min(CHUNK, T);
    for (int id = tid; id < n0 * NSTATE; id += 1024) {
      const int tl = id >> 4, j = id & 15;
      const float rxv = rx[tl];
      float acc = 0.f;
      for (int k = 0; k < H1; ++k) {
        float h = __fadd_rn(__fmul_rn(rxv, W1[k]), b1[k]);  // mul+add, NOT fma
        h = fmaxf(h, 0.f);
        acc = __fmaf_rn(h, W2[k * NSTATE + j], acc);        // sequential-k FMA
      }
      q_lds[0][tl][j] = __fadd_rn(acc, b2[j]);
    }
  }
  __syncthreads();

  // 8 distinct state metrics (trellis rows 8..15 duplicate 0..7)
  float u0 = 0.f, u1 = 0.f, u2 = 0.f, u3 = 0.f,
        u4 = 0.f, u5 = 0.f, u6 = 0.f, u7 = 0.f;
  float mybit = 0.f;

  for (int c = 0; c < nchunks; ++c) {
    const int p = c & 1;
    const int base = c * CHUNK;
    const int nsteps = min(CHUNK, T - base);

    if (tid < 64) {
      // ---- serial ACS on chunk c (byte-identical to passing round 2) ----
      for (int tl = 0; tl < nsteps; ++tl) {
        const int t = base + tl;
        // bit = parity of first argmin of pre-update metrics.
        float m = u0; int arg = 0;
        if (u1 < m) { m = u1; arg = 1; }
        if (u2 < m) { m = u2; arg = 2; }
        if (u3 < m) { m = u3; arg = 3; }
        if (u4 < m) { m = u4; arg = 4; }
        if (u5 < m) { m = u5; arg = 5; }
        if (u6 < m) { m = u6; arg = 6; }
        if (u7 < m) { m = u7; arg = 7; }
        const float bit = (float)(arg & 1);
        if ((t & 63) == lane) mybit = bit;
        if (((t & 63) == 63) || (t == T - 1)) {
          if (lane <= (t & 63)) out[(t & ~63) + lane] = mybit;
        }
        // v[j] = in_prob[j] - prior[j]; in_prob[j] = u[j&7]
        const float* q = q_lds[p][tl];
        const float v0  = __fsub_rn(u0, q[0]),  v1  = __fsub_rn(u1, q[1]);
        const float v2  = __fsub_rn(u2, q[2]),  v3  = __fsub_rn(u3, q[3]);
        const float v4  = __fsub_rn(u4, q[4]),  v5  = __fsub_rn(u5, q[5]);
        const float v6  = __fsub_rn(u6, q[6]),  v7  = __fsub_rn(u7, q[7]);
        const float v8  = __fsub_rn(u0, q[8]),  v9  = __fsub_rn(u1, q[9]);
        const float v10 = __fsub_rn(u2, q[10]), v11 = __fsub_rn(u3, q[11]);
        const float v12 = __fsub_rn(u4, q[12]), v13 = __fsub_rn(u5, q[13]);
        const float v14 = __fsub_rn(u6, q[14]), v15 = __fsub_rn(u7, q[15]);
        u0 = fminf(v0, v1);
        u1 = fminf(v2, v3);
        u2 = fminf(v4, v5);
        u3 = fminf(v6, v7);
        u4 = fminf(v8, v9);
        u5 = fminf(v10, v11);
        u6 = fminf(v12, v13);
        u7 = fminf(v14, v15);
      }
    } else {
      // ---- producers: priors for chunk c+1 into the other buffer ----
      const int nc = c + 1;
      if (nc < nchunks) {
        const int nbase = nc * CHUNK;
        const int nn = min(CHUNK, T - nbase);
        for (int id = tid - 64; id < nn * NSTATE; id += NPROD) {
          const int tl = id >> 4, j = id & 15;
          const float rxv = rx[nbase + tl];
          float acc = 0.f;
          for (int k = 0; k < H1; ++k) {
            float h = __fadd_rn(__fmul_rn(rxv, W1[k]), b1[k]);
            h = fmaxf(h, 0.f);
            acc = __fmaf_rn(h, W2[k * NSTATE + j], acc);
          }
          q_lds[1 - p][tl][j] = __fadd_rn(acc, b2[j]);
        }
      }
    }
    __syncthreads();
  }
}

extern "C" void kernel_launch(void* const* d_in, const int* in_sizes, int n_in,
                              void* d_out, int out_size, void* d_ws, size_t ws_size,
                              hipStream_t stream) {
  const float* rx = (const float*)d_in[0];
  const float* W1 = (const float*)d_in[1];
  const float* b1 = (const float*)d_in[2];
  const float* W2 = (const float*)d_in[3];
  const float* b2 = (const float*)d_in[4];
  float* out = (float*)d_out;
  const int T = in_sizes[0];
  viterbi_pipe2<<<1, 1024, 0, stream>>>(rx, W1, b1, W2, b2, out, T);
}

// Round 5
// 48757.809 us; speedup vs baseline: 2.5658x; 2.1095x over previous
//
#include <hip/hip_runtime.h>

#define NSTATE 16
#define H1 75
#define CHUNK 256
#define NPROD 960  // threads in waves 1..15

// Round 5: lane-parallel serial ACS (one transition per lane, cross-lane via
// shfl), bit extraction deferred via hist + consumer replay. Producers and
// prologue byte-identical to passing round 4. Exact numpy-f32 arithmetic:
// identical IEEE ops in identical order; only the compute LAYOUT changed.
__launch_bounds__(1024, 1)
__global__ void viterbi_lane(const float* __restrict__ rx,
                             const float* __restrict__ W1,
                             const float* __restrict__ b1,
                             const float* __restrict__ W2,
                             const float* __restrict__ b2,
                             float* __restrict__ out, int T) {
  __shared__ float q_lds[2][CHUNK][NSTATE];  // 32 KB priors, double-buffered
  __shared__ float hist[2][CHUNK][8];        // 16 KB pre-update u[0..7] per step
  const int tid = (int)threadIdx.x;
  const int lane = tid & 63;
  const int nchunks = (T + CHUNK - 1) / CHUNK;

  // ---- prologue: priors for chunk 0 (all 1024 threads; identical to r4) ----
  {
    const int n0 = min(CHUNK, T);
    for (int id = tid; id < n0 * NSTATE; id += 1024) {
      const int tl = id >> 4, j = id & 15;
      const float rxv = rx[tl];
      float acc = 0.f;
      for (int k = 0; k < H1; ++k) {
        float h = __fadd_rn(__fmul_rn(rxv, W1[k]), b1[k]);  // mul+add, NOT fma
        h = fmaxf(h, 0.f);
        acc = __fmaf_rn(h, W2[k * NSTATE + j], acc);        // sequential-k FMA
      }
      q_lds[0][tl][j] = __fadd_rn(acc, b2[j]);
    }
  }
  __syncthreads();

  // lane-parallel state: lane j holds w[j] = u[j & 7] (16-transition expansion;
  // lanes 16..63 are replicas of lanes 0..15 and stay consistent).
  const int j = lane & 15;
  // w'[j] = m[(2j) mod 16]; absolute source lane within this 16-group:
  const int perm_src = (lane & 48) | ((2 * j) & 15);
  float w = 0.f;

  for (int c = 0; c < nchunks; ++c) {
    const int p = c & 1;
    const int base = c * CHUNK;
    const int nsteps = min(CHUNK, T - base);

    if (tid < 64) {
      // ---- serial ACS on chunk c, lane-parallel ----
      for (int tl = 0; tl < nsteps; ++tl) {
        // dump pre-update u[0..7] (lanes 0..7 hold exactly u[0..7])
        if (lane < 8) hist[p][tl][lane] = w;
        const float qv = q_lds[p][tl][j];
        const float v = __fsub_rn(w, qv);          // v[j] = u[j&7] - prior[j]
        const float vp = __shfl_xor(v, 1);         // partner transition
        const float m = fminf(v, vp);              // m[j] = u'[j>>1]
        w = __shfl(m, perm_src);                   // w'[j] = u'[j&7]
      }
    } else {
      // ---- producers: priors for chunk c+1 (identical to r4) ----
      const int nc = c + 1;
      if (nc < nchunks) {
        const int nbase = nc * CHUNK;
        const int nn = min(CHUNK, T - nbase);
        for (int id = tid - 64; id < nn * NSTATE; id += NPROD) {
          const int tl = id >> 4, jj = id & 15;
          const float rxv = rx[nbase + tl];
          float acc = 0.f;
          for (int k = 0; k < H1; ++k) {
            float h = __fadd_rn(__fmul_rn(rxv, W1[k]), b1[k]);
            h = fmaxf(h, 0.f);
            acc = __fmaf_rn(h, W2[k * NSTATE + jj], acc);
          }
          q_lds[1 - p][tl][jj] = __fadd_rn(acc, b2[jj]);
        }
      }
      // ---- consumers: bits for chunk c-1 from hist (strict-< first argmin) --
      if (c > 0) {
        const int tl = tid - 64;
        if (tl < CHUNK) {
          const float* h = hist[1 - p][tl];
          float m = h[0]; int arg = 0;
          if (h[1] < m) { m = h[1]; arg = 1; }
          if (h[2] < m) { m = h[2]; arg = 2; }
          if (h[3] < m) { m = h[3]; arg = 3; }
          if (h[4] < m) { m = h[4]; arg = 4; }
          if (h[5] < m) { m = h[5]; arg = 5; }
          if (h[6] < m) { m = h[6]; arg = 6; }
          if (h[7] < m) { m = h[7]; arg = 7; }
          out[(c - 1) * CHUNK + tl] = (float)(arg & 1);
        }
      }
    }
    __syncthreads();
  }

  // ---- epilogue: bits for the last chunk ----
  {
    const int c = nchunks - 1;
    const int p = c & 1;
    const int base = c * CHUNK;
    const int nsteps = T - base;
    if (tid < nsteps) {
      const float* h = hist[p][tid];
      float m = h[0]; int arg = 0;
      if (h[1] < m) { m = h[1]; arg = 1; }
      if (h[2] < m) { m = h[2]; arg = 2; }
      if (h[3] < m) { m = h[3]; arg = 3; }
      if (h[4] < m) { m = h[4]; arg = 4; }
      if (h[5] < m) { m = h[5]; arg = 5; }
      if (h[6] < m) { m = h[6]; arg = 6; }
      if (h[7] < m) { m = h[7]; arg = 7; }
      out[base + tid] = (float)(arg & 1);
    }
  }
}

extern "C" void kernel_launch(void* const* d_in, const int* in_sizes, int n_in,
                              void* d_out, int out_size, void* d_ws, size_t ws_size,
                              hipStream_t stream) {
  const float* rx = (const float*)d_in[0];
  const float* W1 = (const float*)d_in[1];
  const float* b1 = (const float*)d_in[2];
  const float* W2 = (const float*)d_in[3];
  const float* b2 = (const float*)d_in[4];
  float* out = (float*)d_out;
  const int T = in_sizes[0];
  viterbi_lane<<<1, 1024, 0, stream>>>(rx, W1, b1, W2, b2, out, T);
}